// Round 1
// baseline (3758.070 us; speedup 1.0000x reference)
//
#include <hip/hip_runtime.h>
#include <cstdint>
#include <cmath>

// LSTM: B=64, T=2048, H=128, gates=4H=512. f32 throughout (baseline).
// Decomposition:
//   xproj_kernel: xg[b][t][j] = dot(W_ih[j], x[b][t]) + b_ih[j] + b_hh[j]  (parallel GEMM)
//   lstm_rec_kernel: 64 blocks (1 per batch element), 512 threads (thread j owns gate j,
//     W_hh[j][:] in 128 VGPRs), h broadcast via LDS, c in regs of threads 0..127.
// Workspace: [0,32K) h-state, [32K,64K) c-state, [64K, ...) xg chunk buffer.
// Chunked over T if ws_size can't hold the full 256 MB xg.

#define HID 128
#define G4  512
#define BB  64
#define TT  2048

__global__ __launch_bounds__(512, 2)
void xproj_kernel(const float* __restrict__ x, const float* __restrict__ W_ih,
                  const float* __restrict__ b_ih, const float* __restrict__ b_hh,
                  float* __restrict__ xg, int t0, int Tc) {
    __shared__ __align__(16) float xs[64 * HID];   // 64 (b,t)-rows of x
    const int j  = threadIdx.x;                    // gate row 0..511
    const int r0 = blockIdx.x * 64;                // first row of this tile
    const int b   = r0 / Tc;                       // Tc % 64 == 0 -> whole tile same b
    const int tc0 = r0 % Tc;

    // stage 64 x-rows (contiguous in memory: same b, consecutive t)
    const float* xsrc = x + ((size_t)b * TT + (size_t)t0 + tc0) * HID;
    #pragma unroll
    for (int i = 0; i < 4; ++i) {
        const int lin = (i * 512 + j) * 4;         // coalesced float4
        *reinterpret_cast<float4*>(&xs[lin]) =
            *reinterpret_cast<const float4*>(&xsrc[lin]);
    }

    // W_ih row j into registers
    float w[HID];
    const float4* wr = reinterpret_cast<const float4*>(W_ih + (size_t)j * HID);
    #pragma unroll
    for (int k = 0; k < 32; ++k) {
        const float4 v = wr[k];
        w[4*k] = v.x; w[4*k+1] = v.y; w[4*k+2] = v.z; w[4*k+3] = v.w;
    }
    const float bias = b_ih[j] + b_hh[j];
    __syncthreads();

    float* dst = xg + ((size_t)b * Tc + tc0) * G4 + j;
    for (int r = 0; r < 64; ++r) {
        const float4* xr = reinterpret_cast<const float4*>(&xs[r * HID]);
        float acc = bias;
        #pragma unroll
        for (int k = 0; k < 32; ++k) {
            const float4 v = xr[k];                // wave-uniform LDS broadcast
            acc += w[4*k]*v.x + w[4*k+1]*v.y + w[4*k+2]*v.z + w[4*k+3]*v.w;
        }
        dst[(size_t)r * G4] = acc;                 // coalesced across j
    }
}

__global__ __launch_bounds__(512, 2)
void lstm_rec_kernel(const float* __restrict__ xg, const float* __restrict__ h0,
                     const float* __restrict__ c0, const float* __restrict__ W_hh,
                     float* __restrict__ out, float* __restrict__ hstate,
                     float* __restrict__ cstate, int t0, int Tc) {
    __shared__ __align__(16) float h_lds[HID];
    __shared__ __align__(16) float g_lds[G4];
    const int j = threadIdx.x;
    const int b = blockIdx.x;

    // W_hh row j resident in VGPRs
    float w[HID];
    const float4* wr = reinterpret_cast<const float4*>(W_hh + (size_t)j * HID);
    #pragma unroll
    for (int k = 0; k < 32; ++k) {
        const float4 v = wr[k];
        w[4*k] = v.x; w[4*k+1] = v.y; w[4*k+2] = v.z; w[4*k+3] = v.w;
    }

    float c = 0.f;
    if (j < HID) {
        h_lds[j] = (t0 == 0) ? h0[b * HID + j] : hstate[b * HID + j];
        c        = (t0 == 0) ? c0[b * HID + j] : cstate[b * HID + j];
    }
    __syncthreads();

    const float* xgb  = xg  + (size_t)b * Tc * G4 + j;
    float*       outb = out + ((size_t)b * TT + t0) * HID;

    float xnext = xgb[0];                          // prefetched xg for step tc
    for (int tc = 0; tc < Tc; ++tc) {
        float acc = xnext;
        if (tc + 1 < Tc) xnext = xgb[(size_t)(tc + 1) * G4];  // issue early, hide latency

        const float4* h4 = reinterpret_cast<const float4*>(h_lds);
        #pragma unroll
        for (int k = 0; k < 32; ++k) {
            const float4 v = h4[k];                // broadcast read
            acc += w[4*k]*v.x + w[4*k+1]*v.y + w[4*k+2]*v.z + w[4*k+3]*v.w;
        }
        g_lds[j] = acc;
        __syncthreads();                           // all gates ready

        if (j < HID) {
            const float gi = g_lds[j];
            const float gf = g_lds[j +     HID];
            const float gg = g_lds[j + 2 * HID];
            const float go = g_lds[j + 3 * HID];
            const float i_ = 1.f / (1.f + __expf(-gi));
            const float f_ = 1.f / (1.f + __expf(-gf));
            const float g_ = tanhf(gg);
            const float o_ = 1.f / (1.f + __expf(-go));
            c = f_ * c + i_ * g_;
            const float h = o_ * tanhf(c);
            h_lds[j] = h;                          // safe: dots of this step all done
            outb[(size_t)tc * HID + j] = h;        // coalesced 512B store
        }
        __syncthreads();                           // h ready for next step
    }
    if (j < HID) {
        hstate[b * HID + j] = h_lds[j];
        cstate[b * HID + j] = c;
    }
}

extern "C" void kernel_launch(void* const* d_in, const int* in_sizes, int n_in,
                              void* d_out, int out_size, void* d_ws, size_t ws_size,
                              hipStream_t stream) {
    const float* x    = (const float*)d_in[0];
    const float* h0   = (const float*)d_in[1];
    const float* c0   = (const float*)d_in[2];
    const float* W_ih = (const float*)d_in[3];
    const float* W_hh = (const float*)d_in[4];
    const float* b_ih = (const float*)d_in[5];
    const float* b_hh = (const float*)d_in[6];
    float* out = (float*)d_out;

    char*  ws     = (char*)d_ws;
    float* hstate = (float*)ws;                    // 64*128*4 = 32 KB
    float* cstate = (float*)(ws + 32768);          // 32 KB
    float* xg     = (float*)(ws + 65536);

    const size_t per_t = (size_t)BB * G4 * sizeof(float);   // 128 KB per timestep
    size_t avail = ws_size > 65536 ? ws_size - 65536 : 0;
    long long tc_ll = (long long)(avail / per_t);
    int Tc = tc_ll > TT ? TT : (int)tc_ll;
    Tc = (Tc / 64) * 64;
    if (Tc < 64) Tc = 64;                          // minimum chunk (needs ~8.5 MB ws)

    for (int t0 = 0; t0 < TT; t0 += Tc) {
        const int Tcur = (TT - t0 < Tc) ? (TT - t0) : Tc;
        // rows = BB*Tcur, 64 rows per block -> Tcur blocks (BB=64)
        xproj_kernel<<<dim3(Tcur), dim3(512), 0, stream>>>(x, W_ih, b_ih, b_hh, xg, t0, Tcur);
        lstm_rec_kernel<<<dim3(BB), dim3(512), 0, stream>>>(xg, h0, c0, W_hh, out,
                                                            hstate, cstate, t0, Tcur);
    }
}